// Round 5
// baseline (1245.391 us; speedup 1.0000x reference)
//
#include <hip/hip_runtime.h>

// RNN_73813307949430: 4x LSTM(H=50,T=10,F=5) + Dense(50) + Dense(1,sigmoid), B=131072.
// Round 5: occupancy push (2 -> 4 waves/SIMD). Register diet to <=128 total
// (VGPR+AGPR unified on gfx950): B-fragments streamed from L2 per timestep
// (volatile, double-buffered per kt -> 32 regs in flight, not 64 persistent),
// c-state in LDS (fp32, lane-contiguous b128), staging via global_load_lds
// width-16 DMA (no staging registers), __launch_bounds__(256,4).
//
// LDS A = 1024 chunks of 16B: chunk(mt,kt,quad,rr) = ((mt*4+kt)*4+quad)*16+rr
// holds A[row=mt*16+rr][k=kt*32+quad*8+j]. A-frag read for (mt,kt): lane reads
// chunk base+lane -> 16B/lane conflict-free. k 0..63 = X, 64..127 = H.

typedef __attribute__((ext_vector_type(8))) short short8;
typedef __attribute__((ext_vector_type(4))) float floatx4;
typedef __attribute__((ext_vector_type(2))) float float2v;
typedef unsigned short u16;
typedef unsigned int u32;

constexpr int H_ = 50, T_ = 10, F_ = 5;
constexpr int MTILE = 64;   // batch rows per block
constexpr int BLKT = 256;   // 4 waves
constexpr float LOG2E = 1.4426950408889634f;

__device__ __forceinline__ float rcp_(float x) { return __builtin_amdgcn_rcpf(x); }
__device__ __forceinline__ float exp2_(float x) { return __builtin_amdgcn_exp2f(x); }
__device__ __forceinline__ float sig_nat(float x) {
  return rcp_(1.0f + exp2_(-LOG2E * x));
}

__device__ __forceinline__ u16 f2bf(float f) {
  union { float f; unsigned u; } v; v.f = f;
  unsigned r = v.u + 0x7FFFu + ((v.u >> 16) & 1u);  // RNE
  return (u16)(r >> 16);
}
__device__ __forceinline__ float bf2f(u16 s) {
  union { unsigned u; float f; } v; v.u = ((unsigned)s) << 16;
  return v.f;
}
__device__ __forceinline__ unsigned pk_bf16(float a, float b) {
  return (unsigned)f2bf(a) | ((unsigned)f2bf(b) << 16);
}

// async global->LDS DMA, 16B per lane; lds dst = wave-uniform base + lane*16
__device__ __forceinline__ void gload_lds16(const u16* g, u16* l) {
  __builtin_amdgcn_global_load_lds(
      (const __attribute__((address_space(1))) u32*)g,
      (__attribute__((address_space(3))) u32*)l, 16, 0, 0);
}

// ---- prep: swizzle weights into B-fragment order with activation prescale ----
// Wpp[layer][kt][gate][wave][lane][8]; B[k=(lane>>4)*8+j][n=lane&15].
// Gates i,f,o scaled by -log2e; gate g by +2*log2e (exp2-form activations).
__global__ void prep_kernel(
    const float* W1, const float* U1, const float* b1, const float* W2,
    const float* U2, const float* b2, const float* W3, const float* U3,
    const float* b3, const float* W4, const float* U4, const float* b4,
    const float* Wd1, const float* bd1, const float* Wd2, const float* bd2,
    u16* Wpp, float* biasP, float* vdense) {
  int idx = blockIdx.x * blockDim.x + threadIdx.x;
  const float* Wt[4] = {W1, W2, W3, W4};
  const float* Ut[4] = {U1, U2, U3, U4};
  const float* bt[4] = {b1, b2, b3, b4};
  const int fin[4] = {F_, H_, H_, H_};
  if (idx < 4 * 32768) {
    int l = idx >> 15, r = idx & 32767;
    int j = r & 7, lane = (r >> 3) & 63, w = (r >> 9) & 3, gI = (r >> 11) & 3,
        kt = r >> 13;
    int row = kt * 32 + (lane >> 4) * 8 + j;  // K position (0..127)
    int u = w * 16 + (lane & 15);             // unit (0..63)
    float val = 0.0f;
    if (u < H_) {
      if (row < 64) {
        if (row < fin[l]) val = Wt[l][row * 200 + gI * H_ + u];
      } else {
        int rr = row - 64;
        if (rr < H_) val = Ut[l][rr * 200 + gI * H_ + u];
      }
    }
    val *= (gI == 2) ? (2.0f * LOG2E) : (-LOG2E);
    Wpp[idx] = f2bf(val);
  } else if (idx < 4 * 32768 + 1024) {
    int r = idx - 4 * 32768;
    int l = r >> 8, q = r & 255, gI = q >> 6, u = q & 63;
    float val = (u < H_) ? bt[l][gI * H_ + u] : 0.0f;
    biasP[r] = val * ((gI == 2) ? (2.0f * LOG2E) : (-LOG2E));
  } else if (idx < 4 * 32768 + 1024 + 51) {
    int u = idx - (4 * 32768 + 1024);
    if (u < H_) {  // v = Wd1 @ Wd2 (Dense(50) linear -> collapse)
      float s = 0.0f;
      for (int n = 0; n < H_; ++n) s += Wd1[u * H_ + n] * Wd2[n];
      vdense[u] = s;
    } else {
      float s = bd2[0];
      for (int n = 0; n < H_; ++n) s += bd1[n] * Wd2[n];
      vdense[50] = s;
    }
  }
}

// ---- main LSTM layer kernel ----
template <bool FIRST, bool LAST>
__global__ __launch_bounds__(BLKT, 4) void lstm_mfma(
    const float* __restrict__ x0, u16* hbuf, const u16* Wpp,
    const float* __restrict__ biasP, int nblk, const float* __restrict__ vdense,
    float* __restrict__ out) {
  __shared__ __align__(16) u16 A[8192];        // 1024 x 16B chunks
  __shared__ __align__(16) float cbuf[4096];   // c-state [tid][mt] floatx4
  const int tid = threadIdx.x;
  const int w = tid >> 6, lane = tid & 63;
  const int np = lane & 15, quad = lane >> 4;
  const int blk = blockIdx.x;
  const int b0 = blk * MTILE;
  const int u = w * 16 + np;

  float bv[4];
#pragma unroll
  for (int gI = 0; gI < 4; ++gI) bv[gI] = biasP[gI * 64 + u];

  floatx4* cld = (floatx4*)cbuf;
#pragma unroll
  for (int mt = 0; mt < 4; ++mt) cld[tid * 4 + mt] = floatx4{0, 0, 0, 0};

  // zero H region (chunks kk=2,3 of each mt); FIRST also zeroes X region
  for (int i = tid; i < 2048; i += BLKT) {
    int mt = i >> 9, r = i & 511;
    ((u32*)A)[(mt * 256 + 128) * 4 + r] = 0;
  }
  if constexpr (FIRST) {
    for (int i = tid; i < 2048; i += BLKT) {
      int mt = i >> 9, r = i & 511;
      ((u32*)A)[(mt * 256) * 4 + r] = 0;
    }
  }
  __syncthreads();

  const u16* wb = Wpp + w * 512 + lane * 8;  // this wave's B-frag base
  const int kt_u = 2 + (w >> 1);             // h-write chunk coords
  const int cbase =
      ((kt_u * 4 + ((w & 1) * 2 + (np >> 3))) * 16 + quad * 4) * 8 + (np & 7);
  constexpr int NKT = FIRST ? 3 : 4;  // layer 1: k 32..63 all-zero, skip kt=1
  auto ktof = [](int i) { return FIRST ? ((i == 0) ? 0 : (i + 1)) : i; };

  // ---- stage X(0) ----
  if constexpr (FIRST) {
    for (int e = tid; e < MTILE * F_; e += BLKT) {
      int row = e / F_, k = e - row * F_;
      int mt = row >> 4, rr = row & 15;
      A[(mt * 256 + rr) * 8 + k] = f2bf(x0[(size_t)(b0 + row) * (T_ * F_) + k]);
    }
  } else {
    const u16* src = hbuf + (size_t)blk * 4096;
#pragma unroll
    for (int rep = 0; rep < 2; ++rep) {
      int hcb = w * 64 + rep * 256;
      int cb = ((hcb >> 7) * 4 + ((hcb >> 6) & 1)) * 64;
      gload_lds16(src + (size_t)hcb * 8 + lane * 8, &A[cb * 8]);
    }
  }
  __syncthreads();

#pragma unroll 1
  for (int t = 0; t < T_; ++t) {
    // ---- MFMA phase, B streamed from L2 (volatile: defeat LICM re-hoist) ----
    floatx4 acc[4][4];
#pragma unroll
    for (int mt = 0; mt < 4; ++mt)
#pragma unroll
      for (int gI = 0; gI < 4; ++gI)
        acc[mt][gI] = floatx4{bv[gI], bv[gI], bv[gI], bv[gI]};

    short8 bb[2][4];
#pragma unroll
    for (int gI = 0; gI < 4; ++gI)
      bb[0][gI] = *(const volatile short8*)(wb + (ktof(0) * 4 + gI) * 2048);
#pragma unroll
    for (int ki = 0; ki < NKT; ++ki) {
      const int kt = ktof(ki);
      if (ki + 1 < NKT) {
        const int ktn = ktof(ki + 1);
#pragma unroll
        for (int gI = 0; gI < 4; ++gI)
          bb[(ki + 1) & 1][gI] =
              *(const volatile short8*)(wb + (ktn * 4 + gI) * 2048);
      }
#pragma unroll
      for (int mt = 0; mt < 4; ++mt) {
        short8 af = *(const short8*)&A[(((mt * 4 + kt) * 4 + quad) * 16 + np) * 8];
#pragma unroll
        for (int gI = 0; gI < 4; ++gI)
          acc[mt][gI] = __builtin_amdgcn_mfma_f32_16x16x32_bf16(
              af, bb[ki & 1][gI], acc[mt][gI], 0, 0, 0);
      }
    }
    __syncthreads();  // (B) all MFMA reads of X/H done

    // ---- stage X(t+1): overlaps with gate math ----
    if (t + 1 < T_) {
      if constexpr (FIRST) {
        for (int e = tid; e < MTILE * F_; e += BLKT) {
          int row = e / F_, k = e - row * F_;
          int mt = row >> 4, rr = row & 15;
          A[(mt * 256 + rr) * 8 + k] =
              f2bf(x0[(size_t)(b0 + row) * (T_ * F_) + (t + 1) * F_ + k]);
        }
      } else {
        const u16* src = hbuf + ((size_t)(t + 1) * nblk + blk) * 4096;
#pragma unroll
        for (int rep = 0; rep < 2; ++rep) {
          int hcb = w * 64 + rep * 256;
          int cb = ((hcb >> 7) * 4 + ((hcb >> 6) & 1)) * 64;
          gload_lds16(src + (size_t)hcb * 8 + lane * 8, &A[cb * 8]);
        }
      }
    }

    // ---- gates: pairwise packed math, shared rcp, c-state in LDS ----
#pragma unroll
    for (int mt = 0; mt < 4; ++mt) {
      floatx4 cv = cld[tid * 4 + mt];
#pragma unroll
      for (int p = 0; p < 2; ++p) {
        float2v di = {exp2_(acc[mt][0][2 * p]), exp2_(acc[mt][0][2 * p + 1])};
        float2v df = {exp2_(acc[mt][1][2 * p]), exp2_(acc[mt][1][2 * p + 1])};
        float2v dg = {exp2_(acc[mt][2][2 * p]), exp2_(acc[mt][2][2 * p + 1])};
        float2v do_ = {exp2_(acc[mt][3][2 * p]), exp2_(acc[mt][3][2 * p + 1])};
        di += 1.0f; df += 1.0f; dg += 1.0f; do_ += 1.0f;
        float2v m1 = di * df, m2 = do_ * dg;
        float2v P = m1 * m2;
        float Rs = rcp_(P.x * P.y);  // one rcp for 8 factors
        float2v R = {Rs * P.y, Rs * P.x};
        float2v i_ = (df * m2) * R;
        float2v f_ = (di * m2) * R;
        float2v o_ = (m1 * dg) * R;
        float2v g_ = 1.0f - 2.0f * ((m1 * do_) * R);
        float2v cp = {cv[2 * p], cv[2 * p + 1]};
        float2v cn = f_ * cp + i_ * g_;
        cv[2 * p] = cn.x;
        cv[2 * p + 1] = cn.y;
        float2v s = cn * (2.0f * LOG2E);
        float2v dc = {exp2_(s.x), exp2_(s.y)};
        dc += 1.0f;
        float Rc = rcp_(dc.x * dc.y);
        float2v tc = 1.0f - 2.0f * float2v{Rc * dc.y, Rc * dc.x};
        float2v h = o_ * tc;
        unsigned pk = pk_bf16(h.x, h.y);
        int a0 = cbase + mt * 2048 + (2 * p) * 8;
        A[a0] = (u16)pk;
        A[a0 + 8] = (u16)(pk >> 16);
      }
      cld[tid * 4 + mt] = cv;
    }

    // ---- copy-out h_t: wave reads ONLY its own chunks -> no extra barrier ----
    if constexpr (!LAST) {
      u16* dst = hbuf + ((size_t)t * nblk + blk) * 4096;
#pragma unroll
      for (int rep = 0; rep < 2; ++rep) {
        int e = lane + 64 * rep;
        int mt = e >> 5, rem = e & 31, qp = rem >> 4, rr = rem & 15;
        int quad_u = (w & 1) * 2 + qp;
        int ldsc = ((mt * 4 + kt_u) * 4 + quad_u) * 16 + rr;
        int hch = ((mt * 2 + (w >> 1)) * 4 + quad_u) * 16 + rr;
        *(short8*)&dst[(size_t)hch * 8] = *(const short8*)&A[ldsc * 8];
      }
    }
    __syncthreads();  // (A) h + staged X(t+1) visible (drains DMA vmcnt)
  }

  if constexpr (LAST) {
    if (tid < MTILE) {  // out = sigmoid(h . (Wd1@Wd2) + beta)
      int mt = tid >> 4, rr = tid & 15;
      float s = vdense[50];
      for (int k = 0; k < H_; ++k) {
        int ktu = 2 + (k >> 5), qd = (k & 31) >> 3, j = k & 7;
        s += bf2f(A[(((mt * 4 + ktu) * 4 + qd) * 16 + rr) * 8 + j]) * vdense[k];
      }
      out[b0 + tid] = sig_nat(s);
    }
  }
}

extern "C" void kernel_launch(void* const* d_in, const int* in_sizes, int n_in,
                              void* d_out, int out_size, void* d_ws,
                              size_t ws_size, hipStream_t stream) {
  const float* x = (const float*)d_in[0];
  const float* W1 = (const float*)d_in[1];
  const float* U1 = (const float*)d_in[2];
  const float* b1 = (const float*)d_in[3];
  const float* W2 = (const float*)d_in[4];
  const float* U2 = (const float*)d_in[5];
  const float* b2 = (const float*)d_in[6];
  const float* W3 = (const float*)d_in[7];
  const float* U3 = (const float*)d_in[8];
  const float* b3 = (const float*)d_in[9];
  const float* W4 = (const float*)d_in[10];
  const float* U4 = (const float*)d_in[11];
  const float* b4 = (const float*)d_in[12];
  const float* Wd1 = (const float*)d_in[13];
  const float* bd1 = (const float*)d_in[14];
  const float* Wd2 = (const float*)d_in[15];
  const float* bd2 = (const float*)d_in[16];

  const int Bn = in_sizes[0] / (T_ * F_);  // 131072
  const int nblk = Bn / MTILE;             // 2048
  char* ws = (char*)d_ws;
  u16* hbuf = (u16*)ws;  // [T][nblk][512 chunks][8] bf16 = 168 MB
  size_t off = (size_t)T_ * nblk * 4096 * sizeof(u16);
  u16* Wpp = (u16*)(ws + off);                         // 4 x 32768 bf16
  float* biasP = (float*)(ws + off + 262144);          // 4 x 256 f32
  float* vdense = (float*)(ws + off + 262144 + 4096);  // 51 f32
  float* out = (float*)d_out;

  prep_kernel<<<(4 * 32768 + 1024 + 51 + 255) / 256, 256, 0, stream>>>(
      W1, U1, b1, W2, U2, b2, W3, U3, b3, W4, U4, b4, Wd1, bd1, Wd2, bd2, Wpp,
      biasP, vdense);

  dim3 grid(nblk), blkd(BLKT);
  lstm_mfma<true, false><<<grid, blkd, 0, stream>>>(
      x, hbuf, Wpp + 0 * 32768, biasP + 0 * 256, nblk, vdense, nullptr);
  lstm_mfma<false, false><<<grid, blkd, 0, stream>>>(
      nullptr, hbuf, Wpp + 1 * 32768, biasP + 1 * 256, nblk, vdense, nullptr);
  lstm_mfma<false, false><<<grid, blkd, 0, stream>>>(
      nullptr, hbuf, Wpp + 2 * 32768, biasP + 2 * 256, nblk, vdense, nullptr);
  lstm_mfma<false, true><<<grid, blkd, 0, stream>>>(
      nullptr, hbuf, Wpp + 3 * 32768, biasP + 3 * 256, nblk, vdense, out);
}

// Round 6
// 803.171 us; speedup vs baseline: 1.5506x; 1.5506x over previous
//
#include <hip/hip_runtime.h>

// RNN_73813307949430: 4x LSTM(H=50,T=10,F=5) + Dense(50) + Dense(1,sigmoid), B=131072.
// Round 6: R4 structure (B-frags persistent in 64 VGPRs, L2-cached plain loads)
// + occupancy 4 waves/SIMD via mt-SPLIT (acc 32 regs live, 3 barriers/t),
// c-state in LDS as 16 b32 planes (stride-1 dword -> 2-way alias = free),
// staging via global_load_lds DMA (non-volatile path; R5-verified mapping).
//
// LDS A = 1024 chunks of 16B: chunk(mt,kt,quad,rr) = ((mt*4+kt)*4+quad)*16+rr
// holds A[row=mt*16+rr][k=kt*32+quad*8+j]. A-frag read: lane reads chunk
// base+lane -> 16B/lane conflict-free. k 0..63 = X, 64..127 = H (unit u = k-64).

typedef __attribute__((ext_vector_type(8))) short short8;
typedef __attribute__((ext_vector_type(4))) float floatx4;
typedef __attribute__((ext_vector_type(2))) float float2v;
typedef unsigned short u16;
typedef unsigned int u32;

constexpr int H_ = 50, T_ = 10, F_ = 5;
constexpr int MTILE = 64;   // batch rows per block
constexpr int BLKT = 256;   // 4 waves
constexpr float LOG2E = 1.4426950408889634f;

__device__ __forceinline__ float rcp_(float x) { return __builtin_amdgcn_rcpf(x); }
__device__ __forceinline__ float exp2_(float x) { return __builtin_amdgcn_exp2f(x); }
__device__ __forceinline__ float sig_nat(float x) {
  return rcp_(1.0f + exp2_(-LOG2E * x));
}

__device__ __forceinline__ u16 f2bf(float f) {
  union { float f; unsigned u; } v; v.f = f;
  unsigned r = v.u + 0x7FFFu + ((v.u >> 16) & 1u);  // RNE
  return (u16)(r >> 16);
}
__device__ __forceinline__ float bf2f(u16 s) {
  union { unsigned u; float f; } v; v.u = ((unsigned)s) << 16;
  return v.f;
}
__device__ __forceinline__ unsigned pk_bf16(float a, float b) {
  return (unsigned)f2bf(a) | ((unsigned)f2bf(b) << 16);
}

// async global->LDS DMA, 16B per lane; lds dst = wave-uniform base + lane*16
__device__ __forceinline__ void gload_lds16(const u16* g, u16* l) {
  __builtin_amdgcn_global_load_lds(
      (const __attribute__((address_space(1))) u32*)g,
      (__attribute__((address_space(3))) u32*)l, 16, 0, 0);
}

// ---- prep: swizzle weights into B-fragment order with activation prescale ----
// Wpp[layer][kt][gate][wave][lane][8]; B[k=(lane>>4)*8+j][n=lane&15].
// Gates i,f,o scaled by -log2e; gate g by +2*log2e (exp2-form activations).
__global__ void prep_kernel(
    const float* W1, const float* U1, const float* b1, const float* W2,
    const float* U2, const float* b2, const float* W3, const float* U3,
    const float* b3, const float* W4, const float* U4, const float* b4,
    const float* Wd1, const float* bd1, const float* Wd2, const float* bd2,
    u16* Wpp, float* biasP, float* vdense) {
  int idx = blockIdx.x * blockDim.x + threadIdx.x;
  const float* Wt[4] = {W1, W2, W3, W4};
  const float* Ut[4] = {U1, U2, U3, U4};
  const float* bt[4] = {b1, b2, b3, b4};
  const int fin[4] = {F_, H_, H_, H_};
  if (idx < 4 * 32768) {
    int l = idx >> 15, r = idx & 32767;
    int j = r & 7, lane = (r >> 3) & 63, w = (r >> 9) & 3, gI = (r >> 11) & 3,
        kt = r >> 13;
    int row = kt * 32 + (lane >> 4) * 8 + j;  // K position (0..127)
    int u = w * 16 + (lane & 15);             // unit (0..63)
    float val = 0.0f;
    if (u < H_) {
      if (row < 64) {
        if (row < fin[l]) val = Wt[l][row * 200 + gI * H_ + u];
      } else {
        int rr = row - 64;
        if (rr < H_) val = Ut[l][rr * 200 + gI * H_ + u];
      }
    }
    val *= (gI == 2) ? (2.0f * LOG2E) : (-LOG2E);
    Wpp[idx] = f2bf(val);
  } else if (idx < 4 * 32768 + 1024) {
    int r = idx - 4 * 32768;
    int l = r >> 8, q = r & 255, gI = q >> 6, u = q & 63;
    float val = (u < H_) ? bt[l][gI * H_ + u] : 0.0f;
    biasP[r] = val * ((gI == 2) ? (2.0f * LOG2E) : (-LOG2E));
  } else if (idx < 4 * 32768 + 1024 + 51) {
    int u = idx - (4 * 32768 + 1024);
    if (u < H_) {  // v = Wd1 @ Wd2 (Dense(50) linear -> collapse)
      float s = 0.0f;
      for (int n = 0; n < H_; ++n) s += Wd1[u * H_ + n] * Wd2[n];
      vdense[u] = s;
    } else {
      float s = bd2[0];
      for (int n = 0; n < H_; ++n) s += bd1[n] * Wd2[n];
      vdense[50] = s;
    }
  }
}

// ---- main LSTM layer kernel ----
template <bool FIRST, bool LAST>
__global__ __launch_bounds__(BLKT, 4) void lstm_mfma(
    const float* __restrict__ x0, u16* hbuf, const u16* __restrict__ Wpp,
    const float* __restrict__ biasP, int nblk, const float* __restrict__ vdense,
    float* __restrict__ out) {
  __shared__ __align__(16) u16 A[8192];       // 1024 x 16B chunks (16 KB)
  __shared__ float cbuf[16 * 256];            // c-state planes [i][tid] (16 KB)
  const int tid = threadIdx.x;
  const int w = tid >> 6, lane = tid & 63;
  const int np = lane & 15, quad = lane >> 4;
  const int blk = blockIdx.x;
  const int b0 = blk * MTILE;
  const int u = w * 16 + np;

  // B fragments persistent: 16 x short8 = 64 VGPRs, plain (cached) loads.
  short8 bfr[4][4];
#pragma unroll
  for (int kt = 0; kt < 4; ++kt)
#pragma unroll
    for (int gI = 0; gI < 4; ++gI)
      bfr[kt][gI] = *(const short8*)&Wpp[(((kt * 4 + gI) * 4 + w) * 64 + lane) * 8];

  float bv[4];
#pragma unroll
  for (int gI = 0; gI < 4; ++gI) bv[gI] = biasP[gI * 64 + u];

  // zero c-state and H region (chunks kk=2,3); FIRST also zeroes X region
#pragma unroll
  for (int i = 0; i < 16; ++i) cbuf[i * 256 + tid] = 0.0f;
  for (int i = tid; i < 2048; i += BLKT) {
    int mt = i >> 9, r = i & 511;
    ((u32*)A)[(mt * 256 + 128) * 4 + r] = 0;
  }
  if constexpr (FIRST) {
    for (int i = tid; i < 2048; i += BLKT) {
      int mt = i >> 9, r = i & 511;
      ((u32*)A)[(mt * 256) * 4 + r] = 0;
    }
  }
  __syncthreads();

  const int kt_u = 2 + (w >> 1);  // h-write chunk coords for this lane
  const int cbase =
      ((kt_u * 4 + ((w & 1) * 2 + (np >> 3))) * 16 + quad * 4) * 8 + (np & 7);
  constexpr int NKT = FIRST ? 3 : 4;  // layer 1: k 32..63 all-zero, skip kt=1
  auto ktof = [](int i) { return FIRST ? ((i == 0) ? 0 : (i + 1)) : i; };

  // ---- stage X(0) ----
  if constexpr (FIRST) {
    for (int e = tid; e < MTILE * F_; e += BLKT) {
      int row = e / F_, k = e - row * F_;
      int mt = row >> 4, rr = row & 15;
      A[(mt * 256 + rr) * 8 + k] = f2bf(x0[(size_t)(b0 + row) * (T_ * F_) + k]);
    }
  } else {
    const u16* src = hbuf + (size_t)blk * 4096;
#pragma unroll
    for (int rep = 0; rep < 2; ++rep) {
      int hcb = w * 64 + rep * 256;
      int cb = ((hcb >> 7) * 4 + ((hcb >> 6) & 1)) * 64;
      gload_lds16(src + (size_t)hcb * 8 + lane * 8, &A[cb * 8]);
    }
  }
  __syncthreads();

  // MFMA for one mt-half (2 m-tiles), acc = 32 VGPRs live
  auto mfma_half = [&](int m0, floatx4 (&acc)[2][4]) {
#pragma unroll
    for (int mh = 0; mh < 2; ++mh)
#pragma unroll
      for (int gI = 0; gI < 4; ++gI)
        acc[mh][gI] = floatx4{bv[gI], bv[gI], bv[gI], bv[gI]};
#pragma unroll
    for (int ki = 0; ki < NKT; ++ki) {
      const int kt = ktof(ki);
#pragma unroll
      for (int mh = 0; mh < 2; ++mh) {
        short8 af =
            *(const short8*)&A[((((m0 + mh) * 4 + kt) * 4 + quad) * 16 + np) * 8];
#pragma unroll
        for (int gI = 0; gI < 4; ++gI)
          acc[mh][gI] = __builtin_amdgcn_mfma_f32_16x16x32_bf16(
              af, bfr[kt][gI], acc[mh][gI], 0, 0, 0);
      }
    }
  };

  // gates for one mt-half: c in LDS b32 planes, h -> A H-region (own chunks)
  auto gates_half = [&](int m0, floatx4 (&acc)[2][4]) {
#pragma unroll
    for (int mh = 0; mh < 2; ++mh) {
      const int mt = m0 + mh;
#pragma unroll
      for (int p = 0; p < 2; ++p) {
        float2v di = {exp2_(acc[mh][0][2 * p]), exp2_(acc[mh][0][2 * p + 1])};
        float2v df = {exp2_(acc[mh][1][2 * p]), exp2_(acc[mh][1][2 * p + 1])};
        float2v dg = {exp2_(acc[mh][2][2 * p]), exp2_(acc[mh][2][2 * p + 1])};
        float2v do_ = {exp2_(acc[mh][3][2 * p]), exp2_(acc[mh][3][2 * p + 1])};
        di += 1.0f; df += 1.0f; dg += 1.0f; do_ += 1.0f;
        float2v m1 = di * df, m2 = do_ * dg;
        float2v P = m1 * m2;
        float Rs = rcp_(P.x * P.y);  // one rcp for 8 factors
        float2v R = {Rs * P.y, Rs * P.x};
        float2v i_ = (df * m2) * R;
        float2v f_ = (di * m2) * R;
        float2v o_ = (m1 * dg) * R;
        float2v g_ = 1.0f - 2.0f * ((m1 * do_) * R);
        float2v cp = {cbuf[(mt * 4 + 2 * p) * 256 + tid],
                      cbuf[(mt * 4 + 2 * p + 1) * 256 + tid]};
        float2v cn = f_ * cp + i_ * g_;
        cbuf[(mt * 4 + 2 * p) * 256 + tid] = cn.x;
        cbuf[(mt * 4 + 2 * p + 1) * 256 + tid] = cn.y;
        float2v s = cn * (2.0f * LOG2E);
        float2v dc = {exp2_(s.x), exp2_(s.y)};
        dc += 1.0f;
        float Rc = rcp_(dc.x * dc.y);
        float2v tc = 1.0f - 2.0f * float2v{Rc * dc.y, Rc * dc.x};
        float2v h = o_ * tc;
        unsigned pk = pk_bf16(h.x, h.y);
        int a0 = cbase + mt * 2048 + (2 * p) * 8;  // rows quad*4+2p, +1
        A[a0] = (u16)pk;
        A[a0 + 8] = (u16)(pk >> 16);
      }
    }
  };

#pragma unroll 1
  for (int t = 0; t < T_; ++t) {
    floatx4 acc[2][4];

    mfma_half(0, acc);   // reads rows 0-31 (X+H)
    __syncthreads();     // b1: all waves done reading rows 0-31 H
    gates_half(0, acc);  // writes h rows 0-31 (H region)
    mfma_half(2, acc);   // reads rows 32-63 — disjoint from h1 writes
    __syncthreads();     // b2: all waves done reading rows 32-63 H and all X

    // ---- stage X(t+1): overlaps with gates-h2 ----
    if (t + 1 < T_) {
      if constexpr (FIRST) {
        for (int e = tid; e < MTILE * F_; e += BLKT) {
          int row = e / F_, k = e - row * F_;
          int mt = row >> 4, rr = row & 15;
          A[(mt * 256 + rr) * 8 + k] =
              f2bf(x0[(size_t)(b0 + row) * (T_ * F_) + (t + 1) * F_ + k]);
        }
      } else {
        const u16* src = hbuf + ((size_t)(t + 1) * nblk + blk) * 4096;
#pragma unroll
        for (int rep = 0; rep < 2; ++rep) {
          int hcb = w * 64 + rep * 256;
          int cb = ((hcb >> 7) * 4 + ((hcb >> 6) & 1)) * 64;
          gload_lds16(src + (size_t)hcb * 8 + lane * 8, &A[cb * 8]);
        }
      }
    }

    gates_half(2, acc);  // writes h rows 32-63

    // ---- copy-out h_t: wave reads ONLY its own chunks -> no extra barrier ----
    if constexpr (!LAST) {
      u16* dst = hbuf + ((size_t)t * nblk + blk) * 4096;
#pragma unroll
      for (int rep = 0; rep < 2; ++rep) {
        int e = lane + 64 * rep;
        int mt = e >> 5, rem = e & 31, qp = rem >> 4, rr = rem & 15;
        int quad_u = (w & 1) * 2 + qp;
        int ldsc = ((mt * 4 + kt_u) * 4 + quad_u) * 16 + rr;
        int hch = ((mt * 2 + (w >> 1)) * 4 + quad_u) * 16 + rr;
        *(short8*)&dst[(size_t)hch * 8] = *(const short8*)&A[ldsc * 8];
      }
    }
    __syncthreads();  // b3: staged X(t+1) (vmcnt drained) + h visible
  }

  if constexpr (LAST) {
    if (tid < MTILE) {  // out = sigmoid(h . (Wd1@Wd2) + beta)
      int mt = tid >> 4, rr = tid & 15;
      float s = vdense[50];
      for (int k = 0; k < H_; ++k) {
        int ktu = 2 + (k >> 5), qd = (k & 31) >> 3, j = k & 7;
        s += bf2f(A[(((mt * 4 + ktu) * 4 + qd) * 16 + rr) * 8 + j]) * vdense[k];
      }
      out[b0 + tid] = sig_nat(s);
    }
  }
}

extern "C" void kernel_launch(void* const* d_in, const int* in_sizes, int n_in,
                              void* d_out, int out_size, void* d_ws,
                              size_t ws_size, hipStream_t stream) {
  const float* x = (const float*)d_in[0];
  const float* W1 = (const float*)d_in[1];
  const float* U1 = (const float*)d_in[2];
  const float* b1 = (const float*)d_in[3];
  const float* W2 = (const float*)d_in[4];
  const float* U2 = (const float*)d_in[5];
  const float* b2 = (const float*)d_in[6];
  const float* W3 = (const float*)d_in[7];
  const float* U3 = (const float*)d_in[8];
  const float* b3 = (const float*)d_in[9];
  const float* W4 = (const float*)d_in[10];
  const float* U4 = (const float*)d_in[11];
  const float* b4 = (const float*)d_in[12];
  const float* Wd1 = (const float*)d_in[13];
  const float* bd1 = (const float*)d_in[14];
  const float* Wd2 = (const float*)d_in[15];
  const float* bd2 = (const float*)d_in[16];

  const int Bn = in_sizes[0] / (T_ * F_);  // 131072
  const int nblk = Bn / MTILE;             // 2048
  char* ws = (char*)d_ws;
  u16* hbuf = (u16*)ws;  // [T][nblk][512 chunks][8] bf16 = 168 MB
  size_t off = (size_t)T_ * nblk * 4096 * sizeof(u16);
  u16* Wpp = (u16*)(ws + off);                         // 4 x 32768 bf16
  float* biasP = (float*)(ws + off + 262144);          // 4 x 256 f32
  float* vdense = (float*)(ws + off + 262144 + 4096);  // 51 f32
  float* out = (float*)d_out;

  prep_kernel<<<(4 * 32768 + 1024 + 51 + 255) / 256, 256, 0, stream>>>(
      W1, U1, b1, W2, U2, b2, W3, U3, b3, W4, U4, b4, Wd1, bd1, Wd2, bd2, Wpp,
      biasP, vdense);

  dim3 grid(nblk), blkd(BLKT);
  lstm_mfma<true, false><<<grid, blkd, 0, stream>>>(
      x, hbuf, Wpp + 0 * 32768, biasP + 0 * 256, nblk, vdense, nullptr);
  lstm_mfma<false, false><<<grid, blkd, 0, stream>>>(
      nullptr, hbuf, Wpp + 1 * 32768, biasP + 1 * 256, nblk, vdense, nullptr);
  lstm_mfma<false, false><<<grid, blkd, 0, stream>>>(
      nullptr, hbuf, Wpp + 2 * 32768, biasP + 2 * 256, nblk, vdense, nullptr);
  lstm_mfma<false, true><<<grid, blkd, 0, stream>>>(
      nullptr, hbuf, Wpp + 3 * 32768, biasP + 3 * 256, nblk, vdense, out);
}

// Round 7
// 789.171 us; speedup vs baseline: 1.5781x; 1.0177x over previous
//
#include <hip/hip_runtime.h>

// RNN_73813307949430: 4x LSTM(H=50,T=10,F=5) + Dense(50) + Dense(1,sigmoid), B=131072.
// Round 7: R6 occupancy structure (mt-split acc=32 regs, c-state in stride-1 b32
// LDS planes, launch_bounds(256,4), 3 barriers/t) + REGISTER staging prefetch
// (R4 style). global_load_lds DMA reverted: R5/R6 showed DMA reads defeat
// Infinity-Cache residency of the 168 MB inter-layer buffer (FETCH 14->374 MB).
//
// LDS A = 1024 chunks of 16B: chunk(mt,kt,quad,rr) = ((mt*4+kt)*4+quad)*16+rr
// holds A[row=mt*16+rr][k=kt*32+quad*8+j]. A-frag read: lane reads chunk
// base+lane -> 16B/lane conflict-free. k 0..63 = X, 64..127 = H (unit u = k-64).

typedef __attribute__((ext_vector_type(8))) short short8;
typedef __attribute__((ext_vector_type(4))) float floatx4;
typedef __attribute__((ext_vector_type(2))) float float2v;
typedef unsigned short u16;
typedef unsigned int u32;

constexpr int H_ = 50, T_ = 10, F_ = 5;
constexpr int MTILE = 64;   // batch rows per block
constexpr int BLKT = 256;   // 4 waves
constexpr float LOG2E = 1.4426950408889634f;

__device__ __forceinline__ float rcp_(float x) { return __builtin_amdgcn_rcpf(x); }
__device__ __forceinline__ float exp2_(float x) { return __builtin_amdgcn_exp2f(x); }
__device__ __forceinline__ float sig_nat(float x) {
  return rcp_(1.0f + exp2_(-LOG2E * x));
}

__device__ __forceinline__ u16 f2bf(float f) {
  union { float f; unsigned u; } v; v.f = f;
  unsigned r = v.u + 0x7FFFu + ((v.u >> 16) & 1u);  // RNE
  return (u16)(r >> 16);
}
__device__ __forceinline__ float bf2f(u16 s) {
  union { unsigned u; float f; } v; v.u = ((unsigned)s) << 16;
  return v.f;
}
__device__ __forceinline__ unsigned pk_bf16(float a, float b) {
  return (unsigned)f2bf(a) | ((unsigned)f2bf(b) << 16);
}

// ---- prep: swizzle weights into B-fragment order with activation prescale ----
// Wpp[layer][kt][gate][wave][lane][8]; B[k=(lane>>4)*8+j][n=lane&15].
// Gates i,f,o scaled by -log2e; gate g by +2*log2e (exp2-form activations).
__global__ void prep_kernel(
    const float* W1, const float* U1, const float* b1, const float* W2,
    const float* U2, const float* b2, const float* W3, const float* U3,
    const float* b3, const float* W4, const float* U4, const float* b4,
    const float* Wd1, const float* bd1, const float* Wd2, const float* bd2,
    u16* Wpp, float* biasP, float* vdense) {
  int idx = blockIdx.x * blockDim.x + threadIdx.x;
  const float* Wt[4] = {W1, W2, W3, W4};
  const float* Ut[4] = {U1, U2, U3, U4};
  const float* bt[4] = {b1, b2, b3, b4};
  const int fin[4] = {F_, H_, H_, H_};
  if (idx < 4 * 32768) {
    int l = idx >> 15, r = idx & 32767;
    int j = r & 7, lane = (r >> 3) & 63, w = (r >> 9) & 3, gI = (r >> 11) & 3,
        kt = r >> 13;
    int row = kt * 32 + (lane >> 4) * 8 + j;  // K position (0..127)
    int u = w * 16 + (lane & 15);             // unit (0..63)
    float val = 0.0f;
    if (u < H_) {
      if (row < 64) {
        if (row < fin[l]) val = Wt[l][row * 200 + gI * H_ + u];
      } else {
        int rr = row - 64;
        if (rr < H_) val = Ut[l][rr * 200 + gI * H_ + u];
      }
    }
    val *= (gI == 2) ? (2.0f * LOG2E) : (-LOG2E);
    Wpp[idx] = f2bf(val);
  } else if (idx < 4 * 32768 + 1024) {
    int r = idx - 4 * 32768;
    int l = r >> 8, q = r & 255, gI = q >> 6, u = q & 63;
    float val = (u < H_) ? bt[l][gI * H_ + u] : 0.0f;
    biasP[r] = val * ((gI == 2) ? (2.0f * LOG2E) : (-LOG2E));
  } else if (idx < 4 * 32768 + 1024 + 51) {
    int u = idx - (4 * 32768 + 1024);
    if (u < H_) {  // v = Wd1 @ Wd2 (Dense(50) linear -> collapse)
      float s = 0.0f;
      for (int n = 0; n < H_; ++n) s += Wd1[u * H_ + n] * Wd2[n];
      vdense[u] = s;
    } else {
      float s = bd2[0];
      for (int n = 0; n < H_; ++n) s += bd1[n] * Wd2[n];
      vdense[50] = s;
    }
  }
}

// ---- main LSTM layer kernel ----
template <bool FIRST, bool LAST>
__global__ __launch_bounds__(BLKT, 4) void lstm_mfma(
    const float* __restrict__ x0, u16* hbuf, const u16* __restrict__ Wpp,
    const float* __restrict__ biasP, int nblk, const float* __restrict__ vdense,
    float* __restrict__ out) {
  __shared__ __align__(16) u16 A[8192];       // 1024 x 16B chunks (16 KB)
  __shared__ float cbuf[16 * 256];            // c-state planes [i][tid] (16 KB)
  const int tid = threadIdx.x;
  const int w = tid >> 6, lane = tid & 63;
  const int np = lane & 15, quad = lane >> 4;
  const int blk = blockIdx.x;
  const int b0 = blk * MTILE;
  const int u = w * 16 + np;

  // B fragments persistent: 16 x short8 = 64 VGPRs, plain (cached) loads.
  short8 bfr[4][4];
#pragma unroll
  for (int kt = 0; kt < 4; ++kt)
#pragma unroll
    for (int gI = 0; gI < 4; ++gI)
      bfr[kt][gI] = *(const short8*)&Wpp[(((kt * 4 + gI) * 4 + w) * 64 + lane) * 8];

  float bv[4];
#pragma unroll
  for (int gI = 0; gI < 4; ++gI) bv[gI] = biasP[gI * 64 + u];

  // zero c-state and H region (chunks kk=2,3); FIRST also zeroes X region
#pragma unroll
  for (int i = 0; i < 16; ++i) cbuf[i * 256 + tid] = 0.0f;
  for (int i = tid; i < 2048; i += BLKT) {
    int mt = i >> 9, r = i & 511;
    ((u32*)A)[(mt * 256 + 128) * 4 + r] = 0;
  }
  if constexpr (FIRST) {
    for (int i = tid; i < 2048; i += BLKT) {
      int mt = i >> 9, r = i & 511;
      ((u32*)A)[(mt * 256) * 4 + r] = 0;
    }
  }

  const int kt_u = 2 + (w >> 1);  // h-write chunk coords for this lane
  const int cbase =
      ((kt_u * 4 + ((w & 1) * 2 + (np >> 3))) * 16 + quad * 4) * 8 + (np & 7);
  constexpr int NKT = FIRST ? 3 : 4;  // layer 1: k 32..63 all-zero, skip kt=1
  auto ktof = [](int i) { return FIRST ? ((i == 0) ? 0 : (i + 1)) : i; };

  // initial staging prefetch (plain cached loads -> L3-resident hbuf)
  short8 rx0, rx1;
  if constexpr (!FIRST) {
    const u16* s0 = hbuf + (size_t)blk * 4096;
    rx0 = *(const short8*)(s0 + (size_t)tid * 8);
    rx1 = *(const short8*)(s0 + (size_t)(tid + 256) * 8);
  }

  // MFMA for one mt-half (2 m-tiles), acc = 32 VGPRs live
  auto mfma_half = [&](int m0, floatx4 (&acc)[2][4]) {
#pragma unroll
    for (int mh = 0; mh < 2; ++mh)
#pragma unroll
      for (int gI = 0; gI < 4; ++gI)
        acc[mh][gI] = floatx4{bv[gI], bv[gI], bv[gI], bv[gI]};
#pragma unroll
    for (int ki = 0; ki < NKT; ++ki) {
      const int kt = ktof(ki);
#pragma unroll
      for (int mh = 0; mh < 2; ++mh) {
        short8 af =
            *(const short8*)&A[((((m0 + mh) * 4 + kt) * 4 + quad) * 16 + np) * 8];
#pragma unroll
        for (int gI = 0; gI < 4; ++gI)
          acc[mh][gI] = __builtin_amdgcn_mfma_f32_16x16x32_bf16(
              af, bfr[kt][gI], acc[mh][gI], 0, 0, 0);
      }
    }
  };

  // gates for one mt-half: c in LDS b32 planes, h -> A H-region (own chunks)
  auto gates_half = [&](int m0, floatx4 (&acc)[2][4]) {
#pragma unroll
    for (int mh = 0; mh < 2; ++mh) {
      const int mt = m0 + mh;
#pragma unroll
      for (int p = 0; p < 2; ++p) {
        float2v di = {exp2_(acc[mh][0][2 * p]), exp2_(acc[mh][0][2 * p + 1])};
        float2v df = {exp2_(acc[mh][1][2 * p]), exp2_(acc[mh][1][2 * p + 1])};
        float2v dg = {exp2_(acc[mh][2][2 * p]), exp2_(acc[mh][2][2 * p + 1])};
        float2v do_ = {exp2_(acc[mh][3][2 * p]), exp2_(acc[mh][3][2 * p + 1])};
        di += 1.0f; df += 1.0f; dg += 1.0f; do_ += 1.0f;
        float2v m1 = di * df, m2 = do_ * dg;
        float2v P = m1 * m2;
        float Rs = rcp_(P.x * P.y);  // one rcp for 8 factors
        float2v R = {Rs * P.y, Rs * P.x};
        float2v i_ = (df * m2) * R;
        float2v f_ = (di * m2) * R;
        float2v o_ = (m1 * dg) * R;
        float2v g_ = 1.0f - 2.0f * ((m1 * do_) * R);
        float2v cp = {cbuf[(mt * 4 + 2 * p) * 256 + tid],
                      cbuf[(mt * 4 + 2 * p + 1) * 256 + tid]};
        float2v cn = f_ * cp + i_ * g_;
        cbuf[(mt * 4 + 2 * p) * 256 + tid] = cn.x;
        cbuf[(mt * 4 + 2 * p + 1) * 256 + tid] = cn.y;
        float2v s = cn * (2.0f * LOG2E);
        float2v dc = {exp2_(s.x), exp2_(s.y)};
        dc += 1.0f;
        float Rc = rcp_(dc.x * dc.y);
        float2v tc = 1.0f - 2.0f * float2v{Rc * dc.y, Rc * dc.x};
        float2v h = o_ * tc;
        unsigned pk = pk_bf16(h.x, h.y);
        int a0 = cbase + mt * 2048 + (2 * p) * 8;  // rows quad*4+2p, +1
        A[a0] = (u16)pk;
        A[a0 + 8] = (u16)(pk >> 16);
      }
    }
  };

#pragma unroll 1
  for (int t = 0; t < T_; ++t) {
    // ---- stage X(t) from registers; prefetch X(t+1) (clamped, no OOB) ----
    if constexpr (FIRST) {
      for (int e = tid; e < MTILE * F_; e += BLKT) {
        int row = e / F_, k = e - row * F_;
        int mt = row >> 4, rr = row & 15;
        A[(mt * 256 + rr) * 8 + k] =
            f2bf(x0[(size_t)(b0 + row) * (T_ * F_) + t * F_ + k]);
      }
    } else {
      {
        int hc = tid, mt = hc >> 7, kk = (hc >> 6) & 1, rest = hc & 63;
        *(short8*)&A[((mt * 4 + kk) * 64 + rest) * 8] = rx0;
      }
      {
        int hc = tid + 256, mt = hc >> 7, kk = (hc >> 6) & 1, rest = hc & 63;
        *(short8*)&A[((mt * 4 + kk) * 64 + rest) * 8] = rx1;
      }
      const int tn = (t + 1 < T_) ? (t + 1) : 0;  // clamp: avoid OOB, value unused
      const u16* s1 = hbuf + ((size_t)tn * nblk + blk) * 4096;
      rx0 = *(const short8*)(s1 + (size_t)tid * 8);
      rx1 = *(const short8*)(s1 + (size_t)(tid + 256) * 8);
    }
    __syncthreads();  // bA: X(t), h(t-1), c visible to all

    floatx4 acc[2][4];
    mfma_half(0, acc);   // reads X + H rows 0-31
    __syncthreads();     // b1: all waves done reading H rows 0-31
    gates_half(0, acc);  // writes h rows 0-31 (H region)
    mfma_half(2, acc);   // reads X + H rows 32-63 (disjoint from h1 writes)
    __syncthreads();     // b2: all waves done reading H rows 32-63 + all X
    gates_half(2, acc);  // writes h rows 32-63

    // ---- copy-out h_t: wave reads ONLY its own chunks -> no extra barrier ----
    if constexpr (!LAST) {
      u16* dst = hbuf + ((size_t)t * nblk + blk) * 4096;
#pragma unroll
      for (int rep = 0; rep < 2; ++rep) {
        int e = lane + 64 * rep;
        int mt = e >> 5, rem = e & 31, qp = rem >> 4, rr = rem & 15;
        int quad_u = (w & 1) * 2 + qp;
        int ldsc = ((mt * 4 + kt_u) * 4 + quad_u) * 16 + rr;
        int hch = ((mt * 2 + (w >> 1)) * 4 + quad_u) * 16 + rr;
        *(short8*)&dst[(size_t)hch * 8] = *(const short8*)&A[ldsc * 8];
      }
    }
    // next iteration's bA covers h-write visibility; X region writers at loop
    // top only touch chunks whose readers finished at b2.
  }

  if constexpr (LAST) {
    __syncthreads();    // h of t=T-1 (written by all waves) visible
    if (tid < MTILE) {  // out = sigmoid(h . (Wd1@Wd2) + beta)
      int mt = tid >> 4, rr = tid & 15;
      float s = vdense[50];
      for (int k = 0; k < H_; ++k) {
        int ktu = 2 + (k >> 5), qd = (k & 31) >> 3, j = k & 7;
        s += bf2f(A[(((mt * 4 + ktu) * 4 + qd) * 16 + rr) * 8 + j]) * vdense[k];
      }
      out[b0 + tid] = sig_nat(s);
    }
  }
}

extern "C" void kernel_launch(void* const* d_in, const int* in_sizes, int n_in,
                              void* d_out, int out_size, void* d_ws,
                              size_t ws_size, hipStream_t stream) {
  const float* x = (const float*)d_in[0];
  const float* W1 = (const float*)d_in[1];
  const float* U1 = (const float*)d_in[2];
  const float* b1 = (const float*)d_in[3];
  const float* W2 = (const float*)d_in[4];
  const float* U2 = (const float*)d_in[5];
  const float* b2 = (const float*)d_in[6];
  const float* W3 = (const float*)d_in[7];
  const float* U3 = (const float*)d_in[8];
  const float* b3 = (const float*)d_in[9];
  const float* W4 = (const float*)d_in[10];
  const float* U4 = (const float*)d_in[11];
  const float* b4 = (const float*)d_in[12];
  const float* Wd1 = (const float*)d_in[13];
  const float* bd1 = (const float*)d_in[14];
  const float* Wd2 = (const float*)d_in[15];
  const float* bd2 = (const float*)d_in[16];

  const int Bn = in_sizes[0] / (T_ * F_);  // 131072
  const int nblk = Bn / MTILE;             // 2048
  char* ws = (char*)d_ws;
  u16* hbuf = (u16*)ws;  // [T][nblk][512 chunks][8] bf16 = 168 MB
  size_t off = (size_t)T_ * nblk * 4096 * sizeof(u16);
  u16* Wpp = (u16*)(ws + off);                         // 4 x 32768 bf16
  float* biasP = (float*)(ws + off + 262144);          // 4 x 256 f32
  float* vdense = (float*)(ws + off + 262144 + 4096);  // 51 f32
  float* out = (float*)d_out;

  prep_kernel<<<(4 * 32768 + 1024 + 51 + 255) / 256, 256, 0, stream>>>(
      W1, U1, b1, W2, U2, b2, W3, U3, b3, W4, U4, b4, Wd1, bd1, Wd2, bd2, Wpp,
      biasP, vdense);

  dim3 grid(nblk), blkd(BLKT);
  lstm_mfma<true, false><<<grid, blkd, 0, stream>>>(
      x, hbuf, Wpp + 0 * 32768, biasP + 0 * 256, nblk, vdense, nullptr);
  lstm_mfma<false, false><<<grid, blkd, 0, stream>>>(
      nullptr, hbuf, Wpp + 1 * 32768, biasP + 1 * 256, nblk, vdense, nullptr);
  lstm_mfma<false, false><<<grid, blkd, 0, stream>>>(
      nullptr, hbuf, Wpp + 2 * 32768, biasP + 2 * 256, nblk, vdense, nullptr);
  lstm_mfma<false, true><<<grid, blkd, 0, stream>>>(
      nullptr, hbuf, Wpp + 3 * 32768, biasP + 3 * 256, nblk, vdense, out);
}